// Round 18
// baseline (172.035 us; speedup 1.0000x reference)
//
#include <hip/hip_runtime.h>

#define NN 16
#define BB 512
#define DD 256
#define RR (NN*BB)   // 8192

typedef __attribute__((ext_vector_type(8))) short v8s;
typedef __attribute__((ext_vector_type(4))) float v4f;
typedef __attribute__((ext_vector_type(4))) unsigned v4u;

#define MFMA16(a,b,c) __builtin_amdgcn_mfma_f32_16x16x32_bf16((a),(b),(c),0,0,0)

__device__ __forceinline__ unsigned short f2bf(float f){
  unsigned int x = __float_as_uint(f);
  x += 0x7fffu + ((x >> 16) & 1u);
  return (unsigned short)(x >> 16);
}
__device__ __forceinline__ float bf2f(unsigned short u){
  return __uint_as_float(((unsigned int)u) << 16);
}
// packed f32x2 -> bf16x2 (S0 -> low16, S1 -> high16), RTNE — same as f2bf
__device__ __forceinline__ unsigned cvt_pk(float lo, float hi){
  unsigned r;
  asm("v_cvt_pk_bf16_f32 %0, %1, %2" : "=v"(r) : "v"(lo), "v"(hi));
  return r;
}

// ---------- prep kernel (cast + weight transposes + concat, one launch) ----------
// 16x16x32 fragment-order: d = ((k>>5)*NB + (n>>4))*512 + ((k>>3)&3)*128 + (n&15)*8 + (k&7)
// Wcatq: NB=96 (N=1536), K=256. tW2q: NB=32. tW3q: NB=16. iW2q: NB=32. iW3q: NB=16.
__global__ __launch_bounds__(256) void k_prep(
    const float* __restrict__ objs,
    const float* __restrict__ tW1, const float* __restrict__ tW2, const float* __restrict__ tW3,
    const float* __restrict__ iW1, const float* __restrict__ iW2, const float* __restrict__ iW3,
    const float* __restrict__ tb1, const float* __restrict__ ib1,
    unsigned short* __restrict__ objsb,
    unsigned short* __restrict__ Wcatq, unsigned short* __restrict__ tW2q, unsigned short* __restrict__ tW3q,
    unsigned short* __restrict__ iW2q, unsigned short* __restrict__ iW3q,
    float* __restrict__ bcat){
  int idx = blockIdx.x * 256 + threadIdx.x;
  if (idx < 524288){                                   // objs cast, float4 path
    float4 v = ((const float4*)objs)[idx];
    ushort4 o;
    o.x = f2bf(v.x); o.y = f2bf(v.y); o.z = f2bf(v.z); o.w = f2bf(v.w);
    ((ushort4*)objsb)[idx] = o;
    return;
  }
  idx -= 524288;
  if (idx < 131072){                                   // Wcatq cols 0..511 <- tW1 [256][512]
    int n = idx >> 8, k = idx & 255;
    int d = (((k >> 5) * 96 + (n >> 4)) << 9) + (((k >> 3) & 3) << 7) + ((n & 15) << 3) + (k & 7);
    Wcatq[d] = f2bf(tW1[k * 512 + n]);
    return;
  }
  idx -= 131072;
  if (idx < 262144){                                   // tW2q (frag-order) <- tW2 [512][512]
    int n = idx >> 9, k = idx & 511;
    int d = (((k >> 5) * 32 + (n >> 4)) << 9) + (((k >> 3) & 3) << 7) + ((n & 15) << 3) + (k & 7);
    tW2q[d] = f2bf(tW2[k * 512 + n]);
    return;
  }
  idx -= 262144;
  if (idx < 131072){                                   // tW3q (frag-order) <- tW3 [512][256]
    int n = idx >> 9, k = idx & 511;
    int d = (((k >> 5) * 16 + (n >> 4)) << 9) + (((k >> 3) & 3) << 7) + ((n & 15) << 3) + (k & 7);
    tW3q[d] = f2bf(tW3[k * 256 + n]);
    return;
  }
  idx -= 131072;
  if (idx < 262144){                                   // iW2q (16-frag-order) <- iW2 [512][512]
    int n = idx >> 9, k = idx & 511;
    int d = (((k >> 5) * 32 + (n >> 4)) << 9) + (((k >> 3) & 3) << 7) + ((n & 15) << 3) + (k & 7);
    iW2q[d] = f2bf(iW2[k * 512 + n]);
    return;
  }
  idx -= 262144;
  if (idx < 131072){                                   // iW3q (16-frag-order) <- iW3 [512][256]
    int n = idx >> 9, k = idx & 511;
    int d = (((k >> 5) * 16 + (n >> 4)) << 9) + (((k >> 3) & 3) << 7) + ((n & 15) << 3) + (k & 7);
    iW3q[d] = f2bf(iW3[k * 256 + n]);
    return;
  }
  idx -= 131072;
  if (idx < 262144){                                   // Wcatq cols 512..1535 <- iW1 split
    int r = idx >> 8, k = idx & 255;
    float v = (r < 512) ? iW1[k * 512 + r] : iW1[(k + 256) * 512 + (r - 512)];
    int n = 512 + r;
    int d = (((k >> 5) * 96 + (n >> 4)) << 9) + (((k >> 3) & 3) << 7) + ((n & 15) << 3) + (k & 7);
    Wcatq[d] = f2bf(v);
    return;
  }
  idx -= 262144;
  if (idx < 1536)
    bcat[idx] = (idx < 512) ? tb1[idx] : ((idx < 1024) ? 0.f : ib1[idx - 1024]);
}

// ---------- phase-A GEMM C: 128x128 tile, streamed frag-order B ----------
// MODE 0: split epilogue (H1 relu bf16 / UV bf16). MODE 1: relu bf16 out (stride 512).
// MODE 2: T path — float out stride 256, v = relu(c+bias) + extra.
template<int KD, int NBW, int MODE>
__global__ __launch_bounds__(256) void k_gemmC(const unsigned short* __restrict__ A,
                                               const unsigned short* __restrict__ Wq,
                                               const float* __restrict__ bias,
                                               void* __restrict__ Cout,
                                               void* __restrict__ Cout2,
                                               const float* __restrict__ extra){
  __shared__ __align__(16) unsigned char sA[2][16384];   // frag-order [2 k32][8 mf][1KB]
  const int m0 = blockIdx.x * 128;
  const int n0 = blockIdx.y * 128;
  const int t = threadIdx.x;
  const int w = t >> 6, l = t & 63, l15 = l & 15, lq = l >> 4;

  const int sr = t >> 1, sk = (t & 1) << 5;
  const unsigned short* Asrc = A + (size_t)(m0 + sr) * KD + sk;
  const unsigned fbC = (unsigned)(((((sk >> 5) << 3) + (sr >> 4)) << 10) + ((sr & 15) << 4));

  const unsigned short* Wl = Wq + (lq << 7) + (l15 << 3);
  const int nbase = (n0 >> 4) + w * 2;

  v8s a0, a1, a2, a3;
  auto ld_a = [&](int kt){
    a0 = *(const v8s*)(Asrc + kt);
    a1 = *(const v8s*)(Asrc + kt + 8);
    a2 = *(const v8s*)(Asrc + kt + 16);
    a3 = *(const v8s*)(Asrc + kt + 24);
  };
  auto st_a = [&](unsigned char* dst){
    *(v8s*)(dst + fbC) = a0;
    *(v8s*)(dst + fbC + 256) = a1;
    *(v8s*)(dst + fbC + 512) = a2;
    *(v8s*)(dst + fbC + 768) = a3;
  };

  v4f c[8][2];
#pragma unroll
  for (int mf = 0; mf < 8; mf++)
#pragma unroll
    for (int nf = 0; nf < 2; nf++) c[mf][nf] = (v4f){0.f, 0.f, 0.f, 0.f};

  constexpr int S = KD / 64;
  ld_a(0);
  st_a(&sA[0][0]);
  ld_a(64);

#pragma unroll
  for (int s = 0; s < S; ++s){
    __syncthreads();
    const unsigned char* bufc = &sA[s & 1][0];
    { // kb0
      v8s af[8], wf[2];
      const unsigned short* Ws = Wl + ((size_t)((2 * s) * NBW + nbase) << 9);
      wf[0] = *(const v8s*)(Ws);
      wf[1] = *(const v8s*)(Ws + 512);
#pragma unroll
      for (int mf = 0; mf < 8; mf++)
        af[mf] = *(const v8s*)(bufc + (mf << 10) + (l << 4));
#pragma unroll
      for (int mf = 0; mf < 8; mf++)
#pragma unroll
        for (int nf = 0; nf < 2; nf++)
          c[mf][nf] = MFMA16(af[mf], wf[nf], c[mf][nf]);
    }
    if (s + 1 < S) st_a(&sA[(s + 1) & 1][0]);
    if (s + 2 < S) ld_a((s + 2) * 64);
    { // kb1
      v8s af[8], wf[2];
      const unsigned short* Ws = Wl + ((size_t)((2 * s + 1) * NBW + nbase) << 9);
      wf[0] = *(const v8s*)(Ws);
      wf[1] = *(const v8s*)(Ws + 512);
#pragma unroll
      for (int mf = 0; mf < 8; mf++)
        af[mf] = *(const v8s*)(bufc + ((8 + mf) << 10) + (l << 4));
#pragma unroll
      for (int mf = 0; mf < 8; mf++)
#pragma unroll
        for (int nf = 0; nf < 2; nf++)
          c[mf][nf] = MFMA16(af[mf], wf[nf], c[mf][nf]);
    }
  }

#pragma unroll
  for (int mf = 0; mf < 8; mf++){
#pragma unroll
    for (int nf = 0; nf < 2; nf++){
      const int col = n0 + w * 32 + nf * 16 + l15;
      const float bv = bias ? bias[col] : 0.0f;
#pragma unroll
      for (int e = 0; e < 4; e++){
        const int row = m0 + mf * 16 + (lq << 2) + e;
        float v = c[mf][nf][e] + bv;
        if (MODE == 0){
          if (col < 512){
            ((unsigned short*)Cout)[(size_t)row * 512 + col] = f2bf(fmaxf(v, 0.0f));
          } else {
            ((unsigned short*)Cout2)[(size_t)row * 1024 + (col - 512)] = f2bf(v);
          }
        } else if (MODE == 1){
          ((unsigned short*)Cout)[(size_t)row * 512 + col] = f2bf(fmaxf(v, 0.0f));
        } else {
          ((float*)Cout)[(size_t)row * 256 + col] = fmaxf(v, 0.0f) + extra[(size_t)row * 256 + col];
        }
      }
    }
  }
}

// ---------- fused pair kernel — r15 structure (16x16x32, frag-order LDS) ----------
// Plain (cached) P stores this round: L3 (256MB) should absorb the 60MB slab,
// making k_reduce L3-resident instead of HBM-bound. Watch FETCH for L2 thrash.
__global__ __launch_bounds__(512, 2) void k_pair2(
    const unsigned short* __restrict__ UV,   // [8192][1024] bf16: U' | V'+ib1
    const unsigned short* __restrict__ W2q,  // 16-frag-order [16 k32][32 nb][512]
    const unsigned short* __restrict__ W3q,  // 16-frag-order [16 k32][16 nb][512]
    const float* __restrict__ b2,
    const float* __restrict__ b3,
    unsigned short* __restrict__ P){         // [240][131072] bf16 partials (permuted)
  __shared__ __align__(16) unsigned char sA1[2][16384];  // 2 x 16 KB frag-order
  __shared__ __align__(16) unsigned char sA2[131072];    // 128 KB frag-order

  const int bid = blockIdx.x;
  const int xcd = bid & 7;
  const int cc  = bid >> 3;              // 0..119 within XCD
  const int q4  = cc / 30;               // quarter OUTER
  const int pl  = cc - q4 * 30;
  const int p   = xcd * 30 + pl;         // pair 0..239 (i-major per XCD)
  const int i   = p / 15;
  const int rj  = p - i * 15;
  const int j   = rj + (rj >= i ? 1 : 0);
  const int b0  = q4 * 128;

  const int t = threadIdx.x;
  const int w = t >> 6, l = t & 63, l15 = l & 15, lq = l >> 4;
  const int n0w = w * 64;

  const unsigned short* Up = UV + (((size_t)(i * BB + b0)) << 10);
  const unsigned short* Vp = UV + (((size_t)(j * BB + b0)) << 10) + 512;

  const int sr = t >> 2, sk = (t & 3) << 4;
  const size_t srow = (size_t)sr << 10;
  const unsigned fb0 = (unsigned)(((((sk >> 5) << 3) + (sr >> 4)) << 10)
                     + (((sr & 15) + (((sk >> 3) & 3) << 4)) << 4));

  const unsigned short* W2l = W2q + ((size_t)(w * 4) << 9) + (lq << 7) + (l15 << 3);
  const unsigned short* W3l = W3q + (lq << 7) + (l15 << 3);

  v8s u0, u1, v0, v1;

  auto ld_uv = [&](int kt){
    u0 = *(const v8s*)(Up + srow + kt + sk);
    u1 = *(const v8s*)(Up + srow + kt + sk + 8);
    v0 = *(const v8s*)(Vp + srow + kt + sk);
    v1 = *(const v8s*)(Vp + srow + kt + sk + 8);
  };
  auto build_a1 = [&](unsigned char* dst){
    float f0[8], f1[8];
#pragma unroll
    for (int e = 0; e < 8; e++){
      f0[e] = fmaxf(bf2f((unsigned short)u0[e]) + bf2f((unsigned short)v0[e]), 0.f);
      f1[e] = fmaxf(bf2f((unsigned short)u1[e]) + bf2f((unsigned short)v1[e]), 0.f);
    }
    v4u q0, q1;
    q0.x = cvt_pk(f0[0], f0[1]); q0.y = cvt_pk(f0[2], f0[3]);
    q0.z = cvt_pk(f0[4], f0[5]); q0.w = cvt_pk(f0[6], f0[7]);
    q1.x = cvt_pk(f1[0], f1[1]); q1.y = cvt_pk(f1[2], f1[3]);
    q1.z = cvt_pk(f1[4], f1[5]); q1.w = cvt_pk(f1[6], f1[7]);
    *(v4u*)(dst + fb0) = q0;
    *(v4u*)(dst + fb0 + 256) = q1;
  };

  v4f c2[4][8];
#pragma unroll
  for (int nf = 0; nf < 4; nf++)
#pragma unroll
    for (int mf = 0; mf < 8; mf++) c2[nf][mf] = (v4f){0.f, 0.f, 0.f, 0.f};

  ld_uv(0);
  build_a1(&sA1[0][0]);
  ld_uv(64);

#pragma unroll
  for (int s = 0; s < 8; ++s){
    __syncthreads();
    const unsigned char* bufc = &sA1[s & 1][0];
    { // kb0
      v8s a1f[8], w2f[4];
      const unsigned short* W2s = W2l + ((size_t)(s * 2) << 14);
#pragma unroll
      for (int nf = 0; nf < 4; nf++)
        w2f[nf] = *(const v8s*)(W2s + (nf << 9));
#pragma unroll
      for (int mf = 0; mf < 8; mf++)
        a1f[mf] = *(const v8s*)(bufc + (mf << 10) + (l << 4));
      __builtin_amdgcn_s_setprio(1);
#pragma unroll
      for (int nf = 0; nf < 4; nf++)
#pragma unroll
        for (int mf = 0; mf < 8; mf++)
          c2[nf][mf] = MFMA16(w2f[nf], a1f[mf], c2[nf][mf]);
      __builtin_amdgcn_s_setprio(0);
    }
    if (s < 7) build_a1(&sA1[(s + 1) & 1][0]);
    if (s < 6) ld_uv((s + 2) * 64);
    { // kb1
      v8s a1f[8], w2f[4];
      const unsigned short* W2s = W2l + ((size_t)(s * 2 + 1) << 14);
#pragma unroll
      for (int nf = 0; nf < 4; nf++)
        w2f[nf] = *(const v8s*)(W2s + (nf << 9));
#pragma unroll
      for (int mf = 0; mf < 8; mf++)
        a1f[mf] = *(const v8s*)(bufc + ((8 + mf) << 10) + (l << 4));
      __builtin_amdgcn_s_setprio(1);
#pragma unroll
      for (int nf = 0; nf < 4; nf++)
#pragma unroll
        for (int mf = 0; mf < 8; mf++)
          c2[nf][mf] = MFMA16(w2f[nf], a1f[mf], c2[nf][mf]);
      __builtin_amdgcn_s_setprio(0);
    }
  }

  // A2 = relu(c2 + b2) -> sA2 frag-order
#pragma unroll
  for (int nf = 0; nf < 4; nf++){
    const float4 bb = *(const float4*)(b2 + n0w + nf * 16 + (lq << 2));
    const unsigned base = (unsigned)((((w * 2 + (nf >> 1)) << 3) << 10)
                        + ((l15 + (((nf * 2 + (lq >> 1)) & 3) << 4)) << 4)
                        + ((lq & 1) << 3));
#pragma unroll
    for (int mf = 0; mf < 8; mf++){
      v4f vv = c2[nf][mf];
      uint2 u;
      u.x = cvt_pk(fmaxf(vv[0] + bb.x, 0.f), fmaxf(vv[1] + bb.y, 0.f));
      u.y = cvt_pk(fmaxf(vv[2] + bb.z, 0.f), fmaxf(vv[3] + bb.w, 0.f));
      *(uint2*)(sA2 + base + (mf << 10)) = u;
    }
  }
  __syncthreads();

  // GEMM3: barrier-free. wave grid 2m x 4n
  const int wm = w & 1, wn = w >> 1;
  const unsigned short* W3b = W3l + ((size_t)(wn * 4) << 9);
  v4f c3[4][4];
#pragma unroll
  for (int mf = 0; mf < 4; mf++)
#pragma unroll
    for (int nf = 0; nf < 4; nf++) c3[mf][nf] = (v4f){0.f, 0.f, 0.f, 0.f};

#pragma unroll 2
  for (int kb3 = 0; kb3 < 512; kb3 += 32){
    v8s a2f[4], w3f[4];
    const unsigned short* W3s = W3b + ((size_t)(kb3 >> 5) << 13);
#pragma unroll
    for (int nf = 0; nf < 4; nf++)
      w3f[nf] = *(const v8s*)(W3s + (nf << 9));
#pragma unroll
    for (int mf = 0; mf < 4; mf++)
      a2f[mf] = *(const v8s*)(sA2 + ((((kb3 >> 5) << 3) + (wm << 2) + mf) << 10) + (l << 4));
    __builtin_amdgcn_s_setprio(1);
#pragma unroll
    for (int mf = 0; mf < 4; mf++)
#pragma unroll
      for (int nf = 0; nf < 4; nf++)
        c3[mf][nf] = MFMA16(a2f[mf], w3f[nf], c3[mf][nf]);
    __builtin_amdgcn_s_setprio(0);
  }

  // epilogue: packed PLAIN stores into permuted pair slab (L2/L3-cached)
  {
    const float b3v0 = b3[wn * 64 +  0 + l15];
    const float b3v1 = b3[wn * 64 + 16 + l15];
    const float b3v2 = b3[wn * 64 + 32 + l15];
    const float b3v3 = b3[wn * 64 + 48 + l15];
    const int seg = q4 * 2 + wm;
    unsigned short* pb = P + ((size_t)p << 17) + ((size_t)l << 3);
#pragma unroll
    for (int mf = 0; mf < 4; mf++){
      v4u h0, h1;
      h0.x = cvt_pk(fmaxf(c3[mf][0][0] + b3v0, 0.f), fmaxf(c3[mf][0][1] + b3v0, 0.f));
      h0.y = cvt_pk(fmaxf(c3[mf][0][2] + b3v0, 0.f), fmaxf(c3[mf][0][3] + b3v0, 0.f));
      h0.z = cvt_pk(fmaxf(c3[mf][1][0] + b3v1, 0.f), fmaxf(c3[mf][1][1] + b3v1, 0.f));
      h0.w = cvt_pk(fmaxf(c3[mf][1][2] + b3v1, 0.f), fmaxf(c3[mf][1][3] + b3v1, 0.f));
      h1.x = cvt_pk(fmaxf(c3[mf][2][0] + b3v2, 0.f), fmaxf(c3[mf][2][1] + b3v2, 0.f));
      h1.y = cvt_pk(fmaxf(c3[mf][2][2] + b3v2, 0.f), fmaxf(c3[mf][2][3] + b3v2, 0.f));
      h1.z = cvt_pk(fmaxf(c3[mf][3][0] + b3v3, 0.f), fmaxf(c3[mf][3][1] + b3v3, 0.f));
      h1.w = cvt_pk(fmaxf(c3[mf][3][2] + b3v3, 0.f), fmaxf(c3[mf][3][3] + b3v3, 0.f));
      const int B = ((seg * 16 + wn * 4 + mf) << 1);
      *(v4u*)(pb + ((size_t)B << 9)) = h0;
      *(v4u*)(pb + ((size_t)(B + 1) << 9)) = h1;
    }
  }
}

// ---------- slab reduction: out += sum_{15 slabs of i} P (decode permuted) ----------
__global__ __launch_bounds__(256) void k_reduce(const unsigned short* __restrict__ P,
                                                float* __restrict__ out){
  int idx = blockIdx.x * 256 + threadIdx.x;     // 262144 threads, 8 elems each
  const int i = idx >> 14;
  const int g = idx & 16383;                    // = B*64 + l
  const unsigned short* pb = P + (((size_t)(i * 15)) << 17) + ((size_t)g << 3);
  float s[8] = {0.f,0.f,0.f,0.f,0.f,0.f,0.f,0.f};
#pragma unroll
  for (int sl = 0; sl < 15; sl++){
    v8s v = *(const v8s*)(pb + ((size_t)sl << 17));
#pragma unroll
    for (int e = 0; e < 8; e++) s[e] += bf2f((unsigned short)v[e]);
  }
  const int l = g & 63, B = g >> 6;
  const int half = B & 1, mf = (B >> 1) & 3, wn = (B >> 3) & 3, seg = B >> 5;
  const int rowb = (i << 9) + seg * 64 + mf * 16 + ((l >> 4) << 2);
  const int colb = wn * 64 + half * 32 + (l & 15);
  float* ob = out + ((size_t)rowb << 8) + colb;
#pragma unroll
  for (int jj = 0; jj < 2; jj++)
#pragma unroll
    for (int e = 0; e < 4; e++)
      ob[(e << 8) + jj * 16] += s[jj * 4 + e];
}

// ---------- host ----------

extern "C" void kernel_launch(void* const* d_in, const int* in_sizes, int n_in,
                              void* d_out, int out_size, void* d_ws, size_t ws_size,
                              hipStream_t stream){
  const float* objs = (const float*)d_in[0];
  const float* tW1  = (const float*)d_in[1];
  const float* tb1  = (const float*)d_in[2];
  const float* tW2  = (const float*)d_in[3];
  const float* tb2  = (const float*)d_in[4];
  const float* tW3  = (const float*)d_in[5];
  const float* tb3  = (const float*)d_in[6];
  const float* iW1  = (const float*)d_in[7];
  const float* ib1  = (const float*)d_in[8];
  const float* iW2  = (const float*)d_in[9];
  const float* ib2  = (const float*)d_in[10];
  const float* iW3  = (const float*)d_in[11];
  const float* ib3  = (const float*)d_in[12];

  char* ws = (char*)d_ws;
  size_t off = 0;
  unsigned short* objsb = (unsigned short*)(ws + off); off += (size_t)RR * DD * 2;        // 4 MB
  unsigned short* H1    = (unsigned short*)(ws + off); off += (size_t)RR * 512 * 2;       // 8 MB
  unsigned short* H2    = (unsigned short*)(ws + off); off += (size_t)RR * 512 * 2;       // 8 MB
  unsigned short* UVb   = (unsigned short*)(ws + off); off += (size_t)RR * 1024 * 2;      // 16 MB
  unsigned short* Wcatq = (unsigned short*)(ws + off); off += 1536 * 256 * 2;
  unsigned short* tW2q  = (unsigned short*)(ws + off); off += 512 * 512 * 2;
  unsigned short* tW3q  = (unsigned short*)(ws + off); off += 256 * 512 * 2;
  unsigned short* iW2q  = (unsigned short*)(ws + off); off += 512 * 512 * 2;
  unsigned short* iW3q  = (unsigned short*)(ws + off); off += 256 * 512 * 2;
  float*          bcat  = (float*)(ws + off);          off += 1536 * 4;
  unsigned short* P     = (unsigned short*)(ws + off); off += (size_t)240 * 512 * 256 * 2; // 60 MB
  (void)ws_size; (void)in_sizes; (void)n_in; (void)out_size;

  // prep (cast + transposes, one launch)
  k_prep<<<dim3(6662), dim3(256), 0, stream>>>(objs, tW1, tW2, tW3, iW1, iW2, iW3, tb1, ib1,
                                               objsb, Wcatq, tW2q, tW3q, iW2q, iW3q, bcat);

  // merged H1 + UV GEMM (128x128 tiles, streamed frag-B, split epilogue)
  k_gemmC<256, 96, 0><<<dim3(RR / 128, 12), dim3(256), 0, stream>>>(
      objsb, Wcatq, bcat, H1, UVb, nullptr);
  // H2 = relu(H1@tW2+tb2)
  k_gemmC<512, 32, 1><<<dim3(RR / 128, 4), dim3(256), 0, stream>>>(
      H1, tW2q, tb2, H2, nullptr, nullptr);
  // T path: out = relu(H2@tW3+tb3) + objs (streamed frag-B, f32 out)
  k_gemmC<512, 16, 2><<<dim3(RR / 128, 2), dim3(256), 0, stream>>>(
      H2, tW3q, tb3, d_out, nullptr, objs);

  // fused pair interaction -> bf16 permuted partial slabs (cached stores)
  k_pair2<<<dim3(960), dim3(512), 0, stream>>>(UVb, iW2q, iW3q, ib2, ib3, P);

  // out += sum of 15 slabs per i
  k_reduce<<<dim3(1024), dim3(256), 0, stream>>>(P, (float*)d_out);
}

// Round 19
// 165.336 us; speedup vs baseline: 1.0405x; 1.0405x over previous
//
#include <hip/hip_runtime.h>

#define NN 16
#define BB 512
#define DD 256
#define RR (NN*BB)   // 8192

typedef __attribute__((ext_vector_type(8))) short v8s;
typedef __attribute__((ext_vector_type(4))) float v4f;
typedef __attribute__((ext_vector_type(4))) unsigned v4u;

#define MFMA16(a,b,c) __builtin_amdgcn_mfma_f32_16x16x32_bf16((a),(b),(c),0,0,0)

__device__ __forceinline__ unsigned short f2bf(float f){
  unsigned int x = __float_as_uint(f);
  x += 0x7fffu + ((x >> 16) & 1u);
  return (unsigned short)(x >> 16);
}
__device__ __forceinline__ float bf2f(unsigned short u){
  return __uint_as_float(((unsigned int)u) << 16);
}
// packed f32x2 -> bf16x2 (S0 -> low16, S1 -> high16), RTNE — same as f2bf
__device__ __forceinline__ unsigned cvt_pk(float lo, float hi){
  unsigned r;
  asm("v_cvt_pk_bf16_f32 %0, %1, %2" : "=v"(r) : "v"(lo), "v"(hi));
  return r;
}

// ---------- prep kernel (cast + weight transposes + concat, one launch) ----------
// 16x16x32 fragment-order: d = ((k>>5)*NB + (n>>4))*512 + ((k>>3)&3)*128 + (n&15)*8 + (k&7)
// Wcatq: NB=96 (N=1536), K=256.  tW2q: NB=32, K=512.  iW2q: NB=32.  iW3q: NB=16.
__global__ __launch_bounds__(256) void k_prep(
    const float* __restrict__ objs,
    const float* __restrict__ tW1, const float* __restrict__ tW2, const float* __restrict__ tW3,
    const float* __restrict__ iW1, const float* __restrict__ iW2, const float* __restrict__ iW3,
    const float* __restrict__ tb1, const float* __restrict__ ib1,
    unsigned short* __restrict__ objsb,
    unsigned short* __restrict__ Wcatq, unsigned short* __restrict__ tW2q, unsigned short* __restrict__ tW3t,
    unsigned short* __restrict__ iW2q, unsigned short* __restrict__ iW3q,
    float* __restrict__ bcat){
  int idx = blockIdx.x * 256 + threadIdx.x;
  if (idx < 524288){                                   // objs cast, float4 path
    float4 v = ((const float4*)objs)[idx];
    ushort4 o;
    o.x = f2bf(v.x); o.y = f2bf(v.y); o.z = f2bf(v.z); o.w = f2bf(v.w);
    ((ushort4*)objsb)[idx] = o;
    return;
  }
  idx -= 524288;
  if (idx < 131072){                                   // Wcatq cols 0..511 <- tW1 [256][512]
    int n = idx >> 8, k = idx & 255;
    int d = (((k >> 5) * 96 + (n >> 4)) << 9) + (((k >> 3) & 3) << 7) + ((n & 15) << 3) + (k & 7);
    Wcatq[d] = f2bf(tW1[k * 512 + n]);
    return;
  }
  idx -= 131072;
  if (idx < 262144){                                   // tW2q (frag-order) <- tW2 [512][512]
    int n = idx >> 9, k = idx & 511;
    int d = (((k >> 5) * 32 + (n >> 4)) << 9) + (((k >> 3) & 3) << 7) + ((n & 15) << 3) + (k & 7);
    tW2q[d] = f2bf(tW2[k * 512 + n]);
    return;
  }
  idx -= 262144;
  if (idx < 131072){                                   // tW3t [256][512] <- tW3 [512][256]
    int n = idx >> 9, k = idx & 511;
    tW3t[idx] = f2bf(tW3[k * 256 + n]);
    return;
  }
  idx -= 131072;
  if (idx < 262144){                                   // iW2q (16-frag-order) <- iW2 [512][512]
    int n = idx >> 9, k = idx & 511;
    int d = (((k >> 5) * 32 + (n >> 4)) << 9) + (((k >> 3) & 3) << 7) + ((n & 15) << 3) + (k & 7);
    iW2q[d] = f2bf(iW2[k * 512 + n]);
    return;
  }
  idx -= 262144;
  if (idx < 131072){                                   // iW3q (16-frag-order) <- iW3 [512][256]
    int n = idx >> 9, k = idx & 511;
    int d = (((k >> 5) * 16 + (n >> 4)) << 9) + (((k >> 3) & 3) << 7) + ((n & 15) << 3) + (k & 7);
    iW3q[d] = f2bf(iW3[k * 256 + n]);
    return;
  }
  idx -= 131072;
  if (idx < 262144){                                   // Wcatq cols 512..1535 <- iW1 split
    int r = idx >> 8, k = idx & 255;
    float v = (r < 512) ? iW1[k * 512 + r] : iW1[(k + 256) * 512 + (r - 512)];
    int n = 512 + r;
    int d = (((k >> 5) * 96 + (n >> 4)) << 9) + (((k >> 3) & 3) << 7) + ((n & 15) << 3) + (k & 7);
    Wcatq[d] = f2bf(v);
    return;
  }
  idx -= 262144;
  if (idx < 1536)
    bcat[idx] = (idx < 512) ? tb1[idx] : ((idx < 1024) ? 0.f : ib1[idx - 1024]);
}

// ---------- phase-A GEMM, 64x128 tile (kept for the T GEMM) ----------
template<int KD, bool OUTBF16, bool RELU, bool ADDX>
__global__ __launch_bounds__(256) void k_gemm(const unsigned short* __restrict__ A,
                                              const unsigned short* __restrict__ Wt,
                                              const float* __restrict__ bias,
                                              void* __restrict__ Cout,
                                              const float* __restrict__ extra,
                                              int M, int Nn){
  __shared__ __align__(16) unsigned char sA[64 * 128];
  __shared__ __align__(16) unsigned char sB[128 * 128];
  const int m0 = blockIdx.x * 64;
  const int n0 = blockIdx.y * 128;
  const int t = threadIdx.x;
  const int w = t >> 6, l = t & 63;
  const int l15 = l & 15, lq = l >> 4;
  const int rowh = (w & 1) * 32, colh = (w >> 1) * 64;

  v4f c[2][4];
#pragma unroll
  for (int r = 0; r < 2; r++)
#pragma unroll
    for (int q = 0; q < 4; q++) c[r][q] = (v4f){0.f, 0.f, 0.f, 0.f};

  for (int kt = 0; kt < KD; kt += 64){
    __syncthreads();
    {
      const int row = t >> 2, cq = (t & 3) * 16;
      const unsigned short* src = A + (size_t)(m0 + row) * KD + kt + cq;
      v8s a0 = *(const v8s*)(src);
      v8s a1 = *(const v8s*)(src + 8);
      const unsigned sw = (unsigned)((row & 7) << 4);
      *(v8s*)(sA + ((unsigned)((row << 7) + (cq << 1)) ^ sw)) = a0;
      *(v8s*)(sA + ((unsigned)((row << 7) + (cq << 1) + 16) ^ sw)) = a1;
    }
    {
      const int n = t & 127, kq = (t >> 7) * 32;
      const unsigned short* src = Wt + (size_t)(n0 + n) * KD + kt + kq;
      const unsigned base = (unsigned)((n << 7) + (kq << 1));
      const unsigned sw = (unsigned)((n & 7) << 4);
#pragma unroll
      for (int q = 0; q < 4; q++){
        v8s v = *(const v8s*)(src + q * 8);
        *(v8s*)(sB + ((base + q * 16) ^ sw)) = v;
      }
    }
    __syncthreads();
#pragma unroll
    for (int kb = 0; kb < 64; kb += 32){
      v8s af[2], bfr[4];
#pragma unroll
      for (int r = 0; r < 2; r++){
        const int row = rowh + r * 16 + l15;
        af[r] = *(const v8s*)(sA + ((unsigned)((row << 7) + ((kb + (lq << 3)) << 1)) ^ (unsigned)((row & 7) << 4)));
      }
#pragma unroll
      for (int q = 0; q < 4; q++){
        const int n = colh + q * 16 + l15;
        bfr[q] = *(const v8s*)(sB + ((unsigned)((n << 7) + ((kb + (lq << 3)) << 1)) ^ (unsigned)((n & 7) << 4)));
      }
#pragma unroll
      for (int r = 0; r < 2; r++)
#pragma unroll
        for (int q = 0; q < 4; q++)
          c[r][q] = MFMA16(af[r], bfr[q], c[r][q]);
    }
  }
#pragma unroll
  for (int r = 0; r < 2; r++){
#pragma unroll
    for (int q = 0; q < 4; q++){
      const int col = n0 + colh + q * 16 + l15;
      const float bv = bias ? bias[col] : 0.0f;
#pragma unroll
      for (int e = 0; e < 4; e++){
        const int row = m0 + rowh + r * 16 + (lq << 2) + e;
        float v = c[r][q][e] + bv;
        if (RELU) v = fmaxf(v, 0.0f);
        if (ADDX) v += extra[(size_t)row * Nn + col];
        if (OUTBF16) ((unsigned short*)Cout)[(size_t)row * Nn + col] = f2bf(v);
        else         ((float*)Cout)[(size_t)row * Nn + col] = v;
      }
    }
  }
}

// ---------- phase-A GEMM C: 128x128 tile, streamed frag-order B (no sB staging) ----------
template<int KD, int NBW, bool RELU, bool SPLIT>
__global__ __launch_bounds__(256) void k_gemmC(const unsigned short* __restrict__ A,
                                               const unsigned short* __restrict__ Wq,
                                               const float* __restrict__ bias,
                                               void* __restrict__ Cout,
                                               void* __restrict__ Cout2){
  __shared__ __align__(16) unsigned char sA[2][16384];   // frag-order [2 k32][8 mf][1KB]
  const int m0 = blockIdx.x * 128;
  const int n0 = blockIdx.y * 128;
  const int t = threadIdx.x;
  const int w = t >> 6, l = t & 63, l15 = l & 15, lq = l >> 4;

  const int sr = t >> 1, sk = (t & 1) << 5;
  const unsigned short* Asrc = A + (size_t)(m0 + sr) * KD + sk;
  const unsigned fbC = (unsigned)(((((sk >> 5) << 3) + (sr >> 4)) << 10) + ((sr & 15) << 4));

  const unsigned short* Wl = Wq + (lq << 7) + (l15 << 3);
  const int nbase = (n0 >> 4) + w * 2;

  v8s a0, a1, a2, a3;
  auto ld_a = [&](int kt){
    a0 = *(const v8s*)(Asrc + kt);
    a1 = *(const v8s*)(Asrc + kt + 8);
    a2 = *(const v8s*)(Asrc + kt + 16);
    a3 = *(const v8s*)(Asrc + kt + 24);
  };
  auto st_a = [&](unsigned char* dst){
    *(v8s*)(dst + fbC) = a0;
    *(v8s*)(dst + fbC + 256) = a1;
    *(v8s*)(dst + fbC + 512) = a2;
    *(v8s*)(dst + fbC + 768) = a3;
  };

  v4f c[8][2];
#pragma unroll
  for (int mf = 0; mf < 8; mf++)
#pragma unroll
    for (int nf = 0; nf < 2; nf++) c[mf][nf] = (v4f){0.f, 0.f, 0.f, 0.f};

  constexpr int S = KD / 64;
  ld_a(0);
  st_a(&sA[0][0]);
  ld_a(64);

#pragma unroll
  for (int s = 0; s < S; ++s){
    __syncthreads();
    const unsigned char* bufc = &sA[s & 1][0];
    { // kb0
      v8s af[8], wf[2];
      const unsigned short* Ws = Wl + ((size_t)((2 * s) * NBW + nbase) << 9);
      wf[0] = *(const v8s*)(Ws);
      wf[1] = *(const v8s*)(Ws + 512);
#pragma unroll
      for (int mf = 0; mf < 8; mf++)
        af[mf] = *(const v8s*)(bufc + (mf << 10) + (l << 4));
#pragma unroll
      for (int mf = 0; mf < 8; mf++)
#pragma unroll
        for (int nf = 0; nf < 2; nf++)
          c[mf][nf] = MFMA16(af[mf], wf[nf], c[mf][nf]);
    }
    if (s + 1 < S) st_a(&sA[(s + 1) & 1][0]);
    if (s + 2 < S) ld_a((s + 2) * 64);
    { // kb1
      v8s af[8], wf[2];
      const unsigned short* Ws = Wl + ((size_t)((2 * s + 1) * NBW + nbase) << 9);
      wf[0] = *(const v8s*)(Ws);
      wf[1] = *(const v8s*)(Ws + 512);
#pragma unroll
      for (int mf = 0; mf < 8; mf++)
        af[mf] = *(const v8s*)(bufc + ((8 + mf) << 10) + (l << 4));
#pragma unroll
      for (int mf = 0; mf < 8; mf++)
#pragma unroll
        for (int nf = 0; nf < 2; nf++)
          c[mf][nf] = MFMA16(af[mf], wf[nf], c[mf][nf]);
    }
  }

#pragma unroll
  for (int mf = 0; mf < 8; mf++){
#pragma unroll
    for (int nf = 0; nf < 2; nf++){
      const int col = n0 + w * 32 + nf * 16 + l15;
      const float bv = bias ? bias[col] : 0.0f;
#pragma unroll
      for (int e = 0; e < 4; e++){
        const int row = m0 + mf * 16 + (lq << 2) + e;
        float v = c[mf][nf][e] + bv;
        if (SPLIT){
          if (col < 512){
            ((unsigned short*)Cout)[(size_t)row * 512 + col] = f2bf(fmaxf(v, 0.0f));
          } else {
            ((unsigned short*)Cout2)[(size_t)row * 1024 + (col - 512)] = f2bf(v);
          }
        } else {
          if (RELU) v = fmaxf(v, 0.0f);
          ((unsigned short*)Cout)[(size_t)row * 512 + col] = f2bf(v);
        }
      }
    }
  }
}

// ---------- fused pair kernel — r15 proven version (16x16x32, frag-order LDS) ----------
__global__ __launch_bounds__(512, 2) void k_pair2(
    const unsigned short* __restrict__ UV,   // [8192][1024] bf16: U' | V'+ib1
    const unsigned short* __restrict__ W2q,  // 16-frag-order [16 k32][32 nb][512]
    const unsigned short* __restrict__ W3q,  // 16-frag-order [16 k32][16 nb][512]
    const float* __restrict__ b2,
    const float* __restrict__ b3,
    unsigned short* __restrict__ P){         // [240][131072] bf16 partials (permuted)
  __shared__ __align__(16) unsigned char sA1[2][16384];  // 2 x 16 KB frag-order
  __shared__ __align__(16) unsigned char sA2[131072];    // 128 KB frag-order

  const int bid = blockIdx.x;
  const int xcd = bid & 7;
  const int cc  = bid >> 3;              // 0..119 within XCD
  const int q4  = cc / 30;               // quarter OUTER
  const int pl  = cc - q4 * 30;
  const int p   = xcd * 30 + pl;         // pair 0..239 (i-major per XCD)
  const int i   = p / 15;
  const int rj  = p - i * 15;
  const int j   = rj + (rj >= i ? 1 : 0);
  const int b0  = q4 * 128;

  const int t = threadIdx.x;
  const int w = t >> 6, l = t & 63, l15 = l & 15, lq = l >> 4;
  const int n0w = w * 64;

  const unsigned short* Up = UV + (((size_t)(i * BB + b0)) << 10);
  const unsigned short* Vp = UV + (((size_t)(j * BB + b0)) << 10) + 512;

  const int sr = t >> 2, sk = (t & 3) << 4;
  const size_t srow = (size_t)sr << 10;
  const unsigned fb0 = (unsigned)(((((sk >> 5) << 3) + (sr >> 4)) << 10)
                     + (((sr & 15) + (((sk >> 3) & 3) << 4)) << 4));

  const unsigned short* W2l = W2q + ((size_t)(w * 4) << 9) + (lq << 7) + (l15 << 3);
  const unsigned short* W3l = W3q + (lq << 7) + (l15 << 3);

  v8s u0, u1, v0, v1;

  auto ld_uv = [&](int kt){
    u0 = *(const v8s*)(Up + srow + kt + sk);
    u1 = *(const v8s*)(Up + srow + kt + sk + 8);
    v0 = *(const v8s*)(Vp + srow + kt + sk);
    v1 = *(const v8s*)(Vp + srow + kt + sk + 8);
  };
  auto build_a1 = [&](unsigned char* dst){
    float f0[8], f1[8];
#pragma unroll
    for (int e = 0; e < 8; e++){
      f0[e] = fmaxf(bf2f((unsigned short)u0[e]) + bf2f((unsigned short)v0[e]), 0.f);
      f1[e] = fmaxf(bf2f((unsigned short)u1[e]) + bf2f((unsigned short)v1[e]), 0.f);
    }
    v4u q0, q1;
    q0.x = cvt_pk(f0[0], f0[1]); q0.y = cvt_pk(f0[2], f0[3]);
    q0.z = cvt_pk(f0[4], f0[5]); q0.w = cvt_pk(f0[6], f0[7]);
    q1.x = cvt_pk(f1[0], f1[1]); q1.y = cvt_pk(f1[2], f1[3]);
    q1.z = cvt_pk(f1[4], f1[5]); q1.w = cvt_pk(f1[6], f1[7]);
    *(v4u*)(dst + fb0) = q0;
    *(v4u*)(dst + fb0 + 256) = q1;
  };

  v4f c2[4][8];
#pragma unroll
  for (int nf = 0; nf < 4; nf++)
#pragma unroll
    for (int mf = 0; mf < 8; mf++) c2[nf][mf] = (v4f){0.f, 0.f, 0.f, 0.f};

  ld_uv(0);
  build_a1(&sA1[0][0]);
  ld_uv(64);

#pragma unroll
  for (int s = 0; s < 8; ++s){
    __syncthreads();
    const unsigned char* bufc = &sA1[s & 1][0];
    { // kb0
      v8s a1f[8], w2f[4];
      const unsigned short* W2s = W2l + ((size_t)(s * 2) << 14);
#pragma unroll
      for (int nf = 0; nf < 4; nf++)
        w2f[nf] = *(const v8s*)(W2s + (nf << 9));
#pragma unroll
      for (int mf = 0; mf < 8; mf++)
        a1f[mf] = *(const v8s*)(bufc + (mf << 10) + (l << 4));
      __builtin_amdgcn_s_setprio(1);
#pragma unroll
      for (int nf = 0; nf < 4; nf++)
#pragma unroll
        for (int mf = 0; mf < 8; mf++)
          c2[nf][mf] = MFMA16(w2f[nf], a1f[mf], c2[nf][mf]);
      __builtin_amdgcn_s_setprio(0);
    }
    if (s < 7) build_a1(&sA1[(s + 1) & 1][0]);
    if (s < 6) ld_uv((s + 2) * 64);
    { // kb1
      v8s a1f[8], w2f[4];
      const unsigned short* W2s = W2l + ((size_t)(s * 2 + 1) << 14);
#pragma unroll
      for (int nf = 0; nf < 4; nf++)
        w2f[nf] = *(const v8s*)(W2s + (nf << 9));
#pragma unroll
      for (int mf = 0; mf < 8; mf++)
        a1f[mf] = *(const v8s*)(bufc + ((8 + mf) << 10) + (l << 4));
      __builtin_amdgcn_s_setprio(1);
#pragma unroll
      for (int nf = 0; nf < 4; nf++)
#pragma unroll
        for (int mf = 0; mf < 8; mf++)
          c2[nf][mf] = MFMA16(w2f[nf], a1f[mf], c2[nf][mf]);
      __builtin_amdgcn_s_setprio(0);
    }
  }

  // A2 = relu(c2 + b2) -> sA2 frag-order
#pragma unroll
  for (int nf = 0; nf < 4; nf++){
    const float4 bb = *(const float4*)(b2 + n0w + nf * 16 + (lq << 2));
    const unsigned base = (unsigned)((((w * 2 + (nf >> 1)) << 3) << 10)
                        + ((l15 + (((nf * 2 + (lq >> 1)) & 3) << 4)) << 4)
                        + ((lq & 1) << 3));
#pragma unroll
    for (int mf = 0; mf < 8; mf++){
      v4f vv = c2[nf][mf];
      uint2 u;
      u.x = cvt_pk(fmaxf(vv[0] + bb.x, 0.f), fmaxf(vv[1] + bb.y, 0.f));
      u.y = cvt_pk(fmaxf(vv[2] + bb.z, 0.f), fmaxf(vv[3] + bb.w, 0.f));
      *(uint2*)(sA2 + base + (mf << 10)) = u;
    }
  }
  __syncthreads();

  // GEMM3: barrier-free. wave grid 2m x 4n
  const int wm = w & 1, wn = w >> 1;
  const unsigned short* W3b = W3l + ((size_t)(wn * 4) << 9);
  v4f c3[4][4];
#pragma unroll
  for (int mf = 0; mf < 4; mf++)
#pragma unroll
    for (int nf = 0; nf < 4; nf++) c3[mf][nf] = (v4f){0.f, 0.f, 0.f, 0.f};

#pragma unroll 2
  for (int kb3 = 0; kb3 < 512; kb3 += 32){
    v8s a2f[4], w3f[4];
    const unsigned short* W3s = W3b + ((size_t)(kb3 >> 5) << 13);
#pragma unroll
    for (int nf = 0; nf < 4; nf++)
      w3f[nf] = *(const v8s*)(W3s + (nf << 9));
#pragma unroll
    for (int mf = 0; mf < 4; mf++)
      a2f[mf] = *(const v8s*)(sA2 + ((((kb3 >> 5) << 3) + (wm << 2) + mf) << 10) + (l << 4));
    __builtin_amdgcn_s_setprio(1);
#pragma unroll
    for (int mf = 0; mf < 4; mf++)
#pragma unroll
      for (int nf = 0; nf < 4; nf++)
        c3[mf][nf] = MFMA16(a2f[mf], w3f[nf], c3[mf][nf]);
    __builtin_amdgcn_s_setprio(0);
  }

  // epilogue: packed nt stores into permuted pair slab
  {
    const float b3v0 = b3[wn * 64 +  0 + l15];
    const float b3v1 = b3[wn * 64 + 16 + l15];
    const float b3v2 = b3[wn * 64 + 32 + l15];
    const float b3v3 = b3[wn * 64 + 48 + l15];
    const int seg = q4 * 2 + wm;
    unsigned short* pb = P + ((size_t)p << 17) + ((size_t)l << 3);
#pragma unroll
    for (int mf = 0; mf < 4; mf++){
      v4u h0, h1;
      h0.x = cvt_pk(fmaxf(c3[mf][0][0] + b3v0, 0.f), fmaxf(c3[mf][0][1] + b3v0, 0.f));
      h0.y = cvt_pk(fmaxf(c3[mf][0][2] + b3v0, 0.f), fmaxf(c3[mf][0][3] + b3v0, 0.f));
      h0.z = cvt_pk(fmaxf(c3[mf][1][0] + b3v1, 0.f), fmaxf(c3[mf][1][1] + b3v1, 0.f));
      h0.w = cvt_pk(fmaxf(c3[mf][1][2] + b3v1, 0.f), fmaxf(c3[mf][1][3] + b3v1, 0.f));
      h1.x = cvt_pk(fmaxf(c3[mf][2][0] + b3v2, 0.f), fmaxf(c3[mf][2][1] + b3v2, 0.f));
      h1.y = cvt_pk(fmaxf(c3[mf][2][2] + b3v2, 0.f), fmaxf(c3[mf][2][3] + b3v2, 0.f));
      h1.z = cvt_pk(fmaxf(c3[mf][3][0] + b3v3, 0.f), fmaxf(c3[mf][3][1] + b3v3, 0.f));
      h1.w = cvt_pk(fmaxf(c3[mf][3][2] + b3v3, 0.f), fmaxf(c3[mf][3][3] + b3v3, 0.f));
      const int B = ((seg * 16 + wn * 4 + mf) << 1);
      __builtin_nontemporal_store(h0, (v4u*)(pb + ((size_t)B << 9)));
      __builtin_nontemporal_store(h1, (v4u*)(pb + ((size_t)(B + 1) << 9)));
    }
  }
}

// ---------- slab reduction: out += sum_{15 slabs of i} P (decode permuted) ----------
__global__ __launch_bounds__(256) void k_reduce(const unsigned short* __restrict__ P,
                                                float* __restrict__ out){
  int idx = blockIdx.x * 256 + threadIdx.x;     // 262144 threads, 8 elems each
  const int i = idx >> 14;
  const int g = idx & 16383;                    // = B*64 + l
  const unsigned short* pb = P + (((size_t)(i * 15)) << 17) + ((size_t)g << 3);
  float s[8] = {0.f,0.f,0.f,0.f,0.f,0.f,0.f,0.f};
#pragma unroll
  for (int sl = 0; sl < 15; sl++){
    v8s v = __builtin_nontemporal_load((const v8s*)(pb + ((size_t)sl << 17)));
#pragma unroll
    for (int e = 0; e < 8; e++) s[e] += bf2f((unsigned short)v[e]);
  }
  const int l = g & 63, B = g >> 6;
  const int half = B & 1, mf = (B >> 1) & 3, wn = (B >> 3) & 3, seg = B >> 5;
  const int rowb = (i << 9) + seg * 64 + mf * 16 + ((l >> 4) << 2);
  const int colb = wn * 64 + half * 32 + (l & 15);
  float* ob = out + ((size_t)rowb << 8) + colb;
#pragma unroll
  for (int jj = 0; jj < 2; jj++)
#pragma unroll
    for (int e = 0; e < 4; e++)
      ob[(e << 8) + jj * 16] += s[jj * 4 + e];
}

// ---------- host ----------

extern "C" void kernel_launch(void* const* d_in, const int* in_sizes, int n_in,
                              void* d_out, int out_size, void* d_ws, size_t ws_size,
                              hipStream_t stream){
  const float* objs = (const float*)d_in[0];
  const float* tW1  = (const float*)d_in[1];
  const float* tb1  = (const float*)d_in[2];
  const float* tW2  = (const float*)d_in[3];
  const float* tb2  = (const float*)d_in[4];
  const float* tW3  = (const float*)d_in[5];
  const float* tb3  = (const float*)d_in[6];
  const float* iW1  = (const float*)d_in[7];
  const float* ib1  = (const float*)d_in[8];
  const float* iW2  = (const float*)d_in[9];
  const float* ib2  = (const float*)d_in[10];
  const float* iW3  = (const float*)d_in[11];
  const float* ib3  = (const float*)d_in[12];

  char* ws = (char*)d_ws;
  size_t off = 0;
  unsigned short* objsb = (unsigned short*)(ws + off); off += (size_t)RR * DD * 2;        // 4 MB
  unsigned short* H1    = (unsigned short*)(ws + off); off += (size_t)RR * 512 * 2;       // 8 MB
  unsigned short* H2    = (unsigned short*)(ws + off); off += (size_t)RR * 512 * 2;       // 8 MB
  unsigned short* UVb   = (unsigned short*)(ws + off); off += (size_t)RR * 1024 * 2;      // 16 MB
  unsigned short* Wcatq = (unsigned short*)(ws + off); off += 1536 * 256 * 2;
  unsigned short* tW2q  = (unsigned short*)(ws + off); off += 512 * 512 * 2;
  unsigned short* tW3t  = (unsigned short*)(ws + off); off += 256 * 512 * 2;
  unsigned short* iW2q  = (unsigned short*)(ws + off); off += 512 * 512 * 2;
  unsigned short* iW3q  = (unsigned short*)(ws + off); off += 256 * 512 * 2;
  float*          bcat  = (float*)(ws + off);          off += 1536 * 4;
  unsigned short* P     = (unsigned short*)(ws + off); off += (size_t)240 * 512 * 256 * 2; // 60 MB
  (void)ws_size; (void)in_sizes; (void)n_in; (void)out_size;

  // prep (cast + transposes, one launch)
  k_prep<<<dim3(6662), dim3(256), 0, stream>>>(objs, tW1, tW2, tW3, iW1, iW2, iW3, tb1, ib1,
                                               objsb, Wcatq, tW2q, tW3t, iW2q, iW3q, bcat);

  // merged H1 + UV GEMM (128x128 tiles, streamed frag-B, split epilogue)
  k_gemmC<256, 96, false, true ><<<dim3(RR / 128, 12), dim3(256), 0, stream>>>(
      objsb, Wcatq, bcat, H1, UVb);
  // H2 = relu(H1@tW2+tb2)
  k_gemmC<512, 32, true,  false><<<dim3(RR / 128, 4), dim3(256), 0, stream>>>(
      H1, tW2q, tb2, H2, nullptr);
  // T path: out = relu(H2@tW3+tb3) + objs (64x128 tiles, Nn=256)
  k_gemm<512, false, true, true><<<dim3(RR / 64, 2), dim3(256), 0, stream>>>(
      H2, tW3t, tb3, d_out, objs, RR, DD);

  // fused pair interaction -> bf16 permuted partial slabs (nt stores)
  k_pair2<<<dim3(960), dim3(512), 0, stream>>>(UVb, iW2q, iW3q, ib2, ib3, P);

  // out += sum of 15 slabs per i
  k_reduce<<<dim3(1024), dim3(256), 0, stream>>>(P, (float*)d_out);
}